// Round 11
// baseline (504.898 us; speedup 1.0000x reference)
//
#include <hip/hip_runtime.h>
#include <cfloat>
#include <cmath>

#define NB 2
#define NC 34
#define NH 512
#define NW 1024
#define HWSZ (NH*NW)          // 524288 = 2^19
#define TK 200
#define CAPC 49152
#define CHUNK 8192            // LDS sort chunk (64KB) for k_topk
#define ACH 1024              // pixels per block for aggregation kernels
#define ZWORDS (8 + NB*TK*NC + NB*TK)   // ccnt(8, incl. done tickets) + segcnt + pad

// padded layouts
#define PST 1040
#define RPROWS 522            // 5 + 512 + 5
#define RPLEFT 8
#define VPROWS 518            // 3 + 512 + 3
#define VPLEFT 4
#define RPSZ (RPROWS*PST)
#define VPSZ (VPROWS*PST)

typedef unsigned long long u64;

// ---------------- K0: zero accumulators + build padded buffers ----------------
__global__ __launch_bounds__(256) void k_prep(const float* __restrict__ reg,
                                              float* __restrict__ reg_pad,
                                              float* __restrict__ vote_pad,
                                              int* __restrict__ zreg) {
    int t = blockIdx.x * 256 + threadIdx.x;
    if (t < ZWORDS) zreg[t] = 0;               // ccnt[0..1], done ticket zreg[2], segcnt
    if (t < NB * VPSZ) vote_pad[t] = -INFINITY;
    if (t < NB * 2 * RPSZ) {
        int c = t % PST;
        int rest = t / PST;
        int r = rest % RPROWS;
        int bc = rest / RPROWS;                // b*2 + ch
        int rr = r - 5, cc = c - RPLEFT;
        float v = 0.f;
        if (rr >= 0 && rr < NH && cc >= 0 && cc < NW)
            v = reg[(size_t)bc * HWSZ + rr * NW + cc];
        reg_pad[t] = v;
    }
}

#define GETC(f, idx) (((idx)&3)==0 ? f[(idx)>>2].x : ((idx)&3)==1 ? f[(idx)>>2].y : \
                      ((idx)&3)==2 ? f[(idx)>>2].z : f[(idx)>>2].w)

// ---------------- K1: merged seg | vote, block-range partitioned ----------------
// blk%5==0 -> vote block (1024 of 5120), else seg block (4096). Interleaved so
// both classes are co-resident: MEM-bound seg overlaps VALU-bound vote (time ~
// max, not sum). Each path identical to the previous round's standalone kernel
// (bit-exact verified); branch is wave-uniform.
__global__ __launch_bounds__(256, 4) void k_fused1(const float* __restrict__ logits,
                                                   const float* __restrict__ reg_pad,
                                                   float* __restrict__ segmap_out,
                                                   float* __restrict__ mArr,
                                                   float* __restrict__ dArr,
                                                   float* __restrict__ vote_pad) {
    int tid = threadIdx.x;
    int blk = blockIdx.x;
    if (blk % 5 == 0) {
        // ---- vote path ----
        int vblk = blk / 5;
        int b = vblk >> 9;
        int q = vblk & 511;
        int y = ((q & 7) << 6) | (q >> 3);    // XCD-contiguous row bands
        int xb = tid << 2;
        const float* rp0 = reg_pad + (size_t)(b * 2 + 0) * RPSZ;
        const float* rp1 = reg_pad + (size_t)(b * 2 + 1) * RPSZ;
        float a0 = 0.f, a1 = 0.f, a2 = 0.f, a3 = 0.f;
        float4 fA0[5], fA1[5], fB0[5], fB1[5];

        auto loadwin = [&](int i, float4* f0, float4* f1) {
            const float* p0 = rp0 + (size_t)(y + i) * PST + xb;
            const float* p1 = rp1 + (size_t)(y + i) * PST + xb;
#pragma unroll
            for (int t = 0; t < 5; t++) f0[t] = *(const float4*)(p0 + 4 * t);
#pragma unroll
            for (int t = 0; t < 5; t++) f1[t] = *(const float4*)(p1 + 4 * t);
        };
        auto compute = [&](int i, const float4* f0, const float4* f1) {
            int d = i - 5;
            int ad = d < 0 ? -d : d;
            int w = (int)sqrtf((float)(25 - ad * ad));   // exact for {0,9,16,21,24,25}
            int lo = 5 - w, hi = 5 + w;
            float di = (float)d;
#pragma unroll
            for (int j = 0; j < 11; j++) {
                if (j < lo || j > hi) continue;
                float dj = (float)(j - 5);
                float dx, dy, ss;
                dx = __fsub_rn(dj, GETC(f0, j+3)); dy = __fsub_rn(di, GETC(f1, j+3));
                ss = __fadd_rn(__fmul_rn(dx,dx), __fmul_rn(dy,dy));
                a0 = __fadd_rn(a0, sqrtf(ss));
                dx = __fsub_rn(dj, GETC(f0, j+4)); dy = __fsub_rn(di, GETC(f1, j+4));
                ss = __fadd_rn(__fmul_rn(dx,dx), __fmul_rn(dy,dy));
                a1 = __fadd_rn(a1, sqrtf(ss));
                dx = __fsub_rn(dj, GETC(f0, j+5)); dy = __fsub_rn(di, GETC(f1, j+5));
                ss = __fadd_rn(__fmul_rn(dx,dx), __fmul_rn(dy,dy));
                a2 = __fadd_rn(a2, sqrtf(ss));
                dx = __fsub_rn(dj, GETC(f0, j+6)); dy = __fsub_rn(di, GETC(f1, j+6));
                ss = __fadd_rn(__fmul_rn(dx,dx), __fmul_rn(dy,dy));
                a3 = __fadd_rn(a3, sqrtf(ss));
            }
        };

        loadwin(0, fA0, fA1);
#pragma unroll 1
        for (int i = 0; i < 10; i += 2) {
            loadwin(i + 1, fB0, fB1);
            compute(i, fA0, fA1);
            loadwin(i + 2, fA0, fA1);
            compute(i + 1, fB0, fB1);
        }
        compute(10, fA0, fA1);

        float4 vv;
        vv.x = __fsub_rn(-__fdiv_rn(a0, 81.0f), 1.0f);
        vv.y = __fsub_rn(-__fdiv_rn(a1, 81.0f), 1.0f);
        vv.z = __fsub_rn(-__fdiv_rn(a2, 81.0f), 1.0f);
        vv.w = __fsub_rn(-__fdiv_rn(a3, 81.0f), 1.0f);
        *(float4*)(vote_pad + (size_t)b * VPSZ + (size_t)(y + 3) * PST + (xb + VPLEFT)) = vv;
    } else {
        // ---- seg path (two-pass exact softmax stats) ----
        int sblk = blk - blk / 5 - 1;          // bijection onto [0,4096)
        int p = sblk * 256 + tid;
        int b = p >> 19;
        int pix = p & (HWSZ - 1);
        const float* base = logits + (size_t)b * NC * HWSZ + pix;
        float v[NC];
#pragma unroll
        for (int c = 0; c < NC; c++) v[c] = base[(size_t)c * HWSZ];
        float m = -FLT_MAX; int bc = 0;
#pragma unroll
        for (int c = 0; c < NC; c++) { if (v[c] > m) { m = v[c]; bc = c; } }
        float den = 0.f;
#pragma unroll
        for (int c = 0; c < NC; c++) den += expf(v[c] - m);
        segmap_out[p] = (float)bc;
        mArr[p] = m;
        dArr[p] = den;
    }
}

// ---------------- K3: 7x7 max pool, XCD-swizzled, branch-free ----------------
__global__ __launch_bounds__(256) void k_pool(const float* __restrict__ vote_pad,
                                              float* __restrict__ cmap_out,
                                              u64* __restrict__ keys,
                                              int* __restrict__ ccnt,
                                              float thr_keep) {
    int tid = threadIdx.x;
    int blk = blockIdx.x;
    int b = blk >> 9;
    int q = blk & 511;
    int y = ((q & 7) << 6) | (q >> 3);
    int xb = tid << 2;
    const float* vp = vote_pad + (size_t)b * VPSZ;
    float cm[10];
#pragma unroll
    for (int t = 0; t < 10; t++) cm[t] = -INFINITY;
    float vv[4];
#pragma unroll 1
    for (int dy = -3; dy <= 3; dy++) {
        const float* row = vp + (size_t)(y + dy + 3) * PST + xb;
        float4 A = *(const float4*)(row);
        float4 Bq = *(const float4*)(row + 4);
        float4 Cq = *(const float4*)(row + 8);
        float L[12] = {A.x,A.y,A.z,A.w, Bq.x,Bq.y,Bq.z,Bq.w, Cq.x,Cq.y,Cq.z,Cq.w};
#pragma unroll
        for (int t = 0; t < 10; t++) cm[t] = fmaxf(cm[t], L[t + 1]);
        if (dy == 0) { vv[0]=L[4]; vv[1]=L[5]; vv[2]=L[6]; vv[3]=L[7]; }
    }
    int pix = y * NW + xb;
    float cmap[4];
#pragma unroll
    for (int k = 0; k < 4; k++) {
        float mx = cm[k];
#pragma unroll
        for (int u = 1; u < 7; u++) mx = fmaxf(mx, cm[k+u]);
        bool keep = (mx == vv[k]) && (vv[k] > thr_keep);
        cmap[k] = keep ? vv[k] : 0.0f;
        if (keep) {
            int pos = atomicAdd(&ccnt[b], 1);
            if (pos < CAPC) {
                unsigned u = __float_as_uint(vv[k]);
                unsigned ou = ((int)u < 0) ? ~u : (u | 0x80000000u);
                keys[(size_t)b * CAPC + pos] = ((u64)ou << 19) | (u64)(HWSZ - 1 - (pix + k));
            }
        }
    }
    *(float4*)(cmap_out + b * HWSZ + pix) = make_float4(cmap[0],cmap[1],cmap[2],cmap[3]);
}

// Descending bitonic sort. Keys unique (or 0) -> deterministic.
__device__ inline void bitonic_desc(u64* a, int np2, int tid, int T) {
    for (int k = 2; k <= np2; k <<= 1) {
        for (int j = k >> 1; j > 0; j >>= 1) {
            for (int i = tid; i < np2; i += T) {
                int ixj = i ^ j;
                if (ixj > i) {
                    u64 x = a[i], y = a[ixj];
                    bool up = ((i & k) == 0);
                    if (up ? (x < y) : (x > y)) { a[i] = y; a[ixj] = x; }
                }
            }
            __syncthreads();
        }
    }
}

// ---------------- K4: top-200 via LDS bitonic sort ----------------
__global__ __launch_bounds__(1024) void k_topk(const u64* __restrict__ keys_g,
                                               const int* __restrict__ ccnt,
                                               float* __restrict__ cxArr,
                                               float* __restrict__ cyArr,
                                               float* __restrict__ out_centers,
                                               float* __restrict__ out_topvals) {
    __shared__ u64 sk[CHUNK];
    __shared__ u64 cur[512];
    const int T = 1024;
    int b = blockIdx.x;
    int tid = threadIdx.x;
    int n = ccnt[b];
    if (n > CAPC) n = CAPC;
    const u64* Kg = keys_g + (size_t)b * CAPC;
    int nch = (n + CHUNK - 1) / CHUNK;
    if (nch < 1) nch = 1;
    if (tid < 512) cur[tid] = 0;
    __syncthreads();
    for (int ch = 0; ch < nch; ch++) {
        int off = ch * CHUNK;
        int len = n - off; if (len < 0) len = 0; if (len > CHUNK) len = CHUNK;
        int np2 = 256; while (np2 < len) np2 <<= 1;
        for (int c = tid; c < np2; c += T) sk[c] = (c < len) ? Kg[off + c] : 0;
        __syncthreads();
        bitonic_desc(sk, np2, tid, T);
        if (ch == 0) {
            if (tid < TK) cur[tid] = sk[tid];
            __syncthreads();
        } else {
            if (tid < TK) cur[TK + tid] = sk[tid];
            else if (tid < 512) { if (tid >= 2 * TK) cur[tid] = 0; }
            __syncthreads();
            bitonic_desc(cur, 512, tid, T);
        }
    }
    if (tid < TK) {
        u64 w = cur[tid];
        bool valid = (w != 0ULL);
        unsigned ou = (unsigned)(w >> 19);
        unsigned ub = (ou & 0x80000000u) ? (ou & 0x7FFFFFFFu) : ~ou;
        float v = __uint_as_float(ub);
        int pix = valid ? (int)(HWSZ - 1 - (int)(w & 0x7FFFFULL)) : 0x7fffffff;
        int ys = pix >> 10;
        int xs = pix & (NW - 1);
        cxArr[b * TK + tid] = valid ? (float)xs : 1e9f;
        cyArr[b * TK + tid] = valid ? (float)ys : 1e9f;
        out_centers[(b * TK + tid) * 2 + 0] = (float)ys;
        out_centers[(b * TK + tid) * 2 + 1] = (float)xs;
        out_topvals[b * TK + tid] = valid ? v : -INFINITY;
    }
}

// ---------------- K5: assignment + LDS seg_counts + last-block stats ----------------
__global__ __launch_bounds__(256) void k_assign(const float* __restrict__ reg,
                                                const float* __restrict__ segmap,
                                                const float* __restrict__ cxArr,
                                                const float* __restrict__ cyArr,
                                                float* __restrict__ out_inst,
                                                int* __restrict__ segcnt,
                                                int* __restrict__ done,
                                                float* __restrict__ out_icls,
                                                float* __restrict__ out_isize,
                                                float* __restrict__ out_iprob,
                                                int* __restrict__ icls,
                                                int* __restrict__ isize) {
    __shared__ float scx[TK];
    __shared__ float scy[TK];
    __shared__ int lcnt[TK * NC];
    __shared__ int amLast;
    int tid = threadIdx.x;
    int base = blockIdx.x * ACH;
    int b = base >> 19;
    if (tid < TK) {
        scx[tid] = cxArr[b * TK + tid];
        scy[tid] = cyArr[b * TK + tid];
    }
    for (int t = tid; t < TK * NC; t += 256) lcnt[t] = 0;
    __syncthreads();
    const float* r0 = reg + (size_t)b * 2 * HWSZ;
    const float* r1 = r0 + HWSZ;
    int pix0 = (base & (HWSZ - 1)) + tid * 4;
    int y = pix0 >> 10;
    int x0 = pix0 & (NW - 1);
    float4 rx = *(const float4*)(r0 + pix0);
    float4 ry = *(const float4*)(r1 + pix0);
    float px[4], py[4], bd[4];
    int bk[4];
    px[0] = __fsub_rn((float)(x0 + 1), rx.x); py[0] = __fsub_rn((float)(y + 1), ry.x);
    px[1] = __fsub_rn((float)(x0 + 2), rx.y); py[1] = __fsub_rn((float)(y + 1), ry.y);
    px[2] = __fsub_rn((float)(x0 + 3), rx.z); py[2] = __fsub_rn((float)(y + 1), ry.z);
    px[3] = __fsub_rn((float)(x0 + 4), rx.w); py[3] = __fsub_rn((float)(y + 1), ry.w);
#pragma unroll
    for (int it = 0; it < 4; it++) { bd[it] = INFINITY; bk[it] = 0; }
#pragma unroll 4
    for (int k = 0; k < TK; k++) {
        float cx = scx[k];
        float cy = scy[k];
#pragma unroll
        for (int it = 0; it < 4; it++) {
            float dx = __fsub_rn(px[it], cx);
            float dy = __fsub_rn(py[it], cy);
            float d2 = __fadd_rn(__fmul_rn(dx, dx), __fmul_rn(dy, dy));
            if (d2 < bd[it]) { bd[it] = d2; bk[it] = k; }
        }
    }
    float4 sm = *(const float4*)(segmap + base + tid * 4);
    float scls[4] = {sm.x, sm.y, sm.z, sm.w};
    float oi[4];
#pragma unroll
    for (int it = 0; it < 4; it++) {
        int cls = (int)scls[it];
        int thing = (cls >= 24) ? 1 : 0;
        int inst = (bk[it] + 1) * thing;
        oi[it] = (float)inst;
        if (inst) atomicAdd(&lcnt[bk[it] * NC + cls], 1);
    }
    *(float4*)(out_inst + base + tid * 4) = make_float4(oi[0], oi[1], oi[2], oi[3]);
    __syncthreads();
    for (int t = tid; t < TK * NC; t += 256) {
        int v = lcnt[t];
        if (v) atomicAdd(&segcnt[b * TK * NC + t], v);
    }
    // ---- last-block stats phase ----
    __threadfence();                       // release our segcnt contributions
    if (tid == 0) {
        int old = atomicAdd(done, 1);
        amLast = (old == (int)gridDim.x - 1);
    }
    __syncthreads();
    if (!amLast) return;
    __threadfence();                       // acquire
    for (int t = tid; t < NB * TK; t += 256) {
        int total = 0; int bc = 0; int bv = -1;
#pragma unroll
        for (int c = 0; c < NC; c++) {
            // agent-scope atomic loads: coherent-point reads (per-XCD L2 may be stale)
            int v = __hip_atomic_load(&segcnt[t * NC + c], __ATOMIC_RELAXED,
                                      __HIP_MEMORY_SCOPE_AGENT);
            total += v;
            if (v > bv) { bv = v; bc = c; }
        }
        out_icls[t] = (float)bc;
        out_isize[t] = (float)total;
        out_iprob[t] = 0.f;
        icls[t] = bc;
        isize[t] = total;
    }
}

// ---------------- K7: prob sum of selected class -> o_iprob ----------------
__global__ __launch_bounds__(256) void k_probsum(const float* __restrict__ logits,
                                                 const float* __restrict__ inst_f,
                                                 const float* __restrict__ mArr,
                                                 const float* __restrict__ dArr,
                                                 const int* __restrict__ icls,
                                                 const int* __restrict__ isize,
                                                 float* __restrict__ out_iprob) {
    __shared__ float lps[TK];
    int tid = threadIdx.x;
    int base = blockIdx.x * ACH;
    int b = base >> 19;
    for (int t = tid; t < TK; t += 256) lps[t] = 0.f;
    __syncthreads();
    int p0 = base + tid * 4;
    float4 fi = *(const float4*)(inst_f + p0);
    float4 fm = *(const float4*)(mArr + p0);
    float4 fd = *(const float4*)(dArr + p0);
    float insts[4] = {fi.x, fi.y, fi.z, fi.w};
    float ms[4] = {fm.x, fm.y, fm.z, fm.w};
    float ds[4] = {fd.x, fd.y, fd.z, fd.w};
#pragma unroll
    for (int it = 0; it < 4; it++) {
        int inst = (int)insts[it];
        if (inst) {
            int p = p0 + it;
            int pix = p & (HWSZ - 1);
            int c = icls[b * TK + inst - 1];
            float xv = logits[(size_t)(b * NC + c) * HWSZ + pix];
            float pr = __fdiv_rn(expf(__fsub_rn(xv, ms[it])), ds[it]);
            atomicAdd(&lps[inst - 1], pr);
        }
    }
    __syncthreads();
    for (int t = tid; t < TK; t += 256) {
        float s = lps[t];
        if (s != 0.f) {
            float sz = fmaxf((float)isize[b * TK + t], 1.0f);
            atomicAdd(&out_iprob[b * TK + t], s / sz);
        }
    }
}

// Host: replicate _circle_constants threshold exactly (NumPy pairwise sum, f32)
static float compute_thr_keep() {
    float cdm[121];
    int t = 0;
    for (int i = 0; i < 11; i++) {
        for (int j = 0; j < 11; j++) {
            float ox = (float)(j - 5), oy = (float)(i - 5);
            float cd = sqrtf(ox * ox + oy * oy);
            float cm = (cd <= 5.0f) ? 1.0f : 0.0f;
            cdm[t++] = cd * cm;
        }
    }
    float r[8];
    for (int k = 0; k < 8; k++) r[k] = cdm[k];
    int i = 8;
    for (; i < 121 - (121 % 8); i += 8)
        for (int k = 0; k < 8; k++) r[k] += cdm[i + k];
    float res = ((r[0] + r[1]) + (r[2] + r[3])) + ((r[4] + r[5]) + (r[6] + r[7]));
    for (; i < 121; i++) res += cdm[i];
    float thr = res / 81.0f;
    double kt = -(double)thr - 1.0;
    return (float)kt;
}

extern "C" void kernel_launch(void* const* d_in, const int* in_sizes, int n_in,
                              void* d_out, int out_size, void* d_ws, size_t ws_size,
                              hipStream_t stream) {
    const float* logits = (const float*)d_in[0];
    const float* reg    = (const float*)d_in[2];
    float* out = (float*)d_out;

    // output layout (all f32)
    float* o_inst    = out;                       // B*HW
    float* o_seg     = out + 1048576;             // B*HW
    float* o_centers = out + 2097152;             // B*TK*2
    float* o_topvals = out + 2097952;             // B*TK
    float* o_icls    = out + 2098352;             // B*TK
    float* o_iprob   = out + 2098752;             // B*TK
    float* o_isize   = out + 2099152;             // B*TK
    float* o_cmap    = out + 2099552;             // B*HW

    // workspace
    u64* keys = (u64*)d_ws;                                   // NB*CAPC
    float* wsf = (float*)(keys + (size_t)NB * CAPC);
    size_t o = 0;
    int*   zreg    = (int*)(wsf + o); o += ZWORDS;            // [ccnt(2) | done(1) @2 | segcnt]
    int*   ccnt    = zreg;
    int*   done    = zreg + 2;
    int*   segcnt  = zreg + 8;
    float* reg_pad = wsf + o; o += (size_t)NB * 2 * RPSZ;
    float* vote_pad= wsf + o; o += (size_t)NB * VPSZ;
    float* mArr    = wsf + o; o += (size_t)NB * HWSZ;
    float* dArr    = wsf + o; o += (size_t)NB * HWSZ;
    float* cxArr   = wsf + o; o += NB * TK;
    float* cyArr   = wsf + o; o += NB * TK;
    int*   icls    = (int*)(wsf + o); o += NB * TK;
    int*   isize   = (int*)(wsf + o); o += NB * TK;

    float thr_keep = compute_thr_keep();

    int gridPrep  = (NB * 2 * RPSZ + 255) / 256;  // 8483: covers reg_pad (largest region)
    int gridFused = 5120;                          // 4096 seg + 1024 vote, interleaved
    int gridRow   = NB * NH;                       // 1024
    int gridAgg   = (NB * HWSZ) / ACH;             // 1024

    k_prep<<<gridPrep, 256, 0, stream>>>(reg, reg_pad, vote_pad, zreg);
    k_fused1<<<gridFused, 256, 0, stream>>>(logits, reg_pad, o_seg, mArr, dArr, vote_pad);
    k_pool<<<gridRow, 256, 0, stream>>>(vote_pad, o_cmap, keys, ccnt, thr_keep);
    k_topk<<<NB, 1024, 0, stream>>>(keys, ccnt, cxArr, cyArr, o_centers, o_topvals);
    k_assign<<<gridAgg, 256, 0, stream>>>(reg, o_seg, cxArr, cyArr, o_inst, segcnt,
                                          done, o_icls, o_isize, o_iprob, icls, isize);
    k_probsum<<<gridAgg, 256, 0, stream>>>(logits, o_inst, mArr, dArr, icls, isize, o_iprob);
}

// Round 12
// 455.688 us; speedup vs baseline: 1.1080x; 1.1080x over previous
//
#include <hip/hip_runtime.h>
#include <cfloat>
#include <cmath>

#define NB 2
#define NC 34
#define NH 512
#define NW 1024
#define HWSZ (NH*NW)          // 524288 = 2^19
#define TK 200
#define CAPC 49152
#define CHUNK 8192            // LDS sort chunk (64KB)
#define ACH 1024              // pixels per block (probsum)
#define ACH8 2048             // pixels per block (assign, 8 px/thread)
#define ZWORDS (8 + NB*TK*NC + NB*TK)

// padded layouts
#define PST 1040
#define RPROWS 522            // 5 + 512 + 5
#define RPLEFT 8
#define VPROWS 518            // 3 + 512 + 3
#define VPLEFT 4
#define RPSZ (RPROWS*PST)
#define VPSZ (VPROWS*PST)

typedef unsigned long long u64;

// ---------------- K1: softmax stats + zero-fold + padded-buffer prep ----------------
__global__ __launch_bounds__(256) void k_seg(const float* __restrict__ logits,
                                             const float* __restrict__ reg,
                                             float* __restrict__ segmap_out,
                                             float* __restrict__ mArr,
                                             float* __restrict__ dArr,
                                             float* __restrict__ reg_pad,
                                             float* __restrict__ vote_pad,
                                             int* __restrict__ zreg) {
    int p = blockIdx.x * 256 + threadIdx.x;
    if (p < ZWORDS) zreg[p] = 0;
    for (int t = p; t < NB * 2 * RPSZ; t += NB * HWSZ) {
        int c = t % PST;
        int rest = t / PST;
        int r = rest % RPROWS;
        int bc = rest / RPROWS;            // b*2 + ch
        int rr = r - 5, cc = c - RPLEFT;
        float v = 0.f;
        if (rr >= 0 && rr < NH && cc >= 0 && cc < NW)
            v = reg[(size_t)bc * HWSZ + rr * NW + cc];
        reg_pad[t] = v;
    }
    for (int t = p; t < NB * VPSZ; t += NB * HWSZ) vote_pad[t] = -INFINITY;
    if (p >= NB * HWSZ) return;
    int b = p >> 19;
    int pix = p & (HWSZ - 1);
    const float* base = logits + (size_t)b * NC * HWSZ + pix;
    float v[NC];
#pragma unroll
    for (int c = 0; c < NC; c++) v[c] = base[(size_t)c * HWSZ];
    float m = -FLT_MAX; int bc = 0;
#pragma unroll
    for (int c = 0; c < NC; c++) { if (v[c] > m) { m = v[c]; bc = c; } }
    float den = 0.f;
#pragma unroll
    for (int c = 0; c < NC; c++) den += expf(v[c] - m);
    segmap_out[p] = (float)bc;
    mArr[p] = m;
    dArr[p] = den;
}

#define GETC(f, idx) (((idx)&3)==0 ? f[(idx)>>2].x : ((idx)&3)==1 ? f[(idx)>>2].y : \
                      ((idx)&3)==2 ? f[(idx)>>2].z : f[(idx)>>2].w)

// ---------------- K2: vote map, XCD-swizzled rows, branch-free aligned loads ----------------
__global__ __launch_bounds__(256, 4) void k_vote(const float* __restrict__ reg_pad,
                                                 float* __restrict__ vote_pad) {
    int tid = threadIdx.x;
    int blk = blockIdx.x;
    int b = blk >> 9;
    int q = blk & 511;
    int y = ((q & 7) << 6) | (q >> 3);    // XCD-contiguous row bands
    int xb = tid << 2;
    const float* rp0 = reg_pad + (size_t)(b * 2 + 0) * RPSZ;
    const float* rp1 = reg_pad + (size_t)(b * 2 + 1) * RPSZ;
    float a0 = 0.f, a1 = 0.f, a2 = 0.f, a3 = 0.f;

    float4 fA0[5], fA1[5], fB0[5], fB1[5];

    auto loadwin = [&](int i, float4* f0, float4* f1) {
        const float* p0 = rp0 + (size_t)(y + i) * PST + xb;
        const float* p1 = rp1 + (size_t)(y + i) * PST + xb;
#pragma unroll
        for (int t = 0; t < 5; t++) f0[t] = *(const float4*)(p0 + 4 * t);
#pragma unroll
        for (int t = 0; t < 5; t++) f1[t] = *(const float4*)(p1 + 4 * t);
    };

    auto compute = [&](int i, const float4* f0, const float4* f1) {
        int d = i - 5;
        int ad = d < 0 ? -d : d;
        int w = (int)sqrtf((float)(25 - ad * ad));   // exact for {0,9,16,21,24,25}
        int lo = 5 - w, hi = 5 + w;
        float di = (float)d;
#pragma unroll
        for (int j = 0; j < 11; j++) {
            if (j < lo || j > hi) continue;
            float dj = (float)(j - 5);
            float dx, dy, ss;
            dx = __fsub_rn(dj, GETC(f0, j+3)); dy = __fsub_rn(di, GETC(f1, j+3));
            ss = __fadd_rn(__fmul_rn(dx,dx), __fmul_rn(dy,dy));
            a0 = __fadd_rn(a0, sqrtf(ss));
            dx = __fsub_rn(dj, GETC(f0, j+4)); dy = __fsub_rn(di, GETC(f1, j+4));
            ss = __fadd_rn(__fmul_rn(dx,dx), __fmul_rn(dy,dy));
            a1 = __fadd_rn(a1, sqrtf(ss));
            dx = __fsub_rn(dj, GETC(f0, j+5)); dy = __fsub_rn(di, GETC(f1, j+5));
            ss = __fadd_rn(__fmul_rn(dx,dx), __fmul_rn(dy,dy));
            a2 = __fadd_rn(a2, sqrtf(ss));
            dx = __fsub_rn(dj, GETC(f0, j+6)); dy = __fsub_rn(di, GETC(f1, j+6));
            ss = __fadd_rn(__fmul_rn(dx,dx), __fmul_rn(dy,dy));
            a3 = __fadd_rn(a3, sqrtf(ss));
        }
    };

    loadwin(0, fA0, fA1);
#pragma unroll 1
    for (int i = 0; i < 10; i += 2) {
        loadwin(i + 1, fB0, fB1);
        compute(i, fA0, fA1);
        loadwin(i + 2, fA0, fA1);
        compute(i + 1, fB0, fB1);
    }
    compute(10, fA0, fA1);

    float4 vv;
    vv.x = __fsub_rn(-__fdiv_rn(a0, 81.0f), 1.0f);
    vv.y = __fsub_rn(-__fdiv_rn(a1, 81.0f), 1.0f);
    vv.z = __fsub_rn(-__fdiv_rn(a2, 81.0f), 1.0f);
    vv.w = __fsub_rn(-__fdiv_rn(a3, 81.0f), 1.0f);
    *(float4*)(vote_pad + (size_t)b * VPSZ + (size_t)(y + 3) * PST + (xb + VPLEFT)) = vv;
}

// ---------------- K3: 7x7 max pool, XCD-swizzled, branch-free ----------------
__global__ __launch_bounds__(256) void k_pool(const float* __restrict__ vote_pad,
                                              float* __restrict__ cmap_out,
                                              u64* __restrict__ keys,
                                              int* __restrict__ ccnt,
                                              float thr_keep) {
    int tid = threadIdx.x;
    int blk = blockIdx.x;
    int b = blk >> 9;
    int q = blk & 511;
    int y = ((q & 7) << 6) | (q >> 3);
    int xb = tid << 2;
    const float* vp = vote_pad + (size_t)b * VPSZ;
    float cm[10];
#pragma unroll
    for (int t = 0; t < 10; t++) cm[t] = -INFINITY;
    float vv[4];
#pragma unroll 1
    for (int dy = -3; dy <= 3; dy++) {
        const float* row = vp + (size_t)(y + dy + 3) * PST + xb;
        float4 A = *(const float4*)(row);
        float4 Bq = *(const float4*)(row + 4);
        float4 Cq = *(const float4*)(row + 8);
        float L[12] = {A.x,A.y,A.z,A.w, Bq.x,Bq.y,Bq.z,Bq.w, Cq.x,Cq.y,Cq.z,Cq.w};
#pragma unroll
        for (int t = 0; t < 10; t++) cm[t] = fmaxf(cm[t], L[t + 1]);
        if (dy == 0) { vv[0]=L[4]; vv[1]=L[5]; vv[2]=L[6]; vv[3]=L[7]; }
    }
    int pix = y * NW + xb;
    float cmap[4];
#pragma unroll
    for (int k = 0; k < 4; k++) {
        float mx = cm[k];
#pragma unroll
        for (int u = 1; u < 7; u++) mx = fmaxf(mx, cm[k+u]);
        bool keep = (mx == vv[k]) && (vv[k] > thr_keep);
        cmap[k] = keep ? vv[k] : 0.0f;
        if (keep) {
            int pos = atomicAdd(&ccnt[b], 1);
            if (pos < CAPC) {
                unsigned u = __float_as_uint(vv[k]);
                unsigned ou = ((int)u < 0) ? ~u : (u | 0x80000000u);
                keys[(size_t)b * CAPC + pos] = ((u64)ou << 19) | (u64)(HWSZ - 1 - (pix + k));
            }
        }
    }
    *(float4*)(cmap_out + b * HWSZ + pix) = make_float4(cmap[0],cmap[1],cmap[2],cmap[3]);
}

// Descending bitonic sort. Keys unique (or 0) -> deterministic.
__device__ inline void bitonic_desc(u64* a, int np2, int tid, int T) {
    for (int k = 2; k <= np2; k <<= 1) {
        for (int j = k >> 1; j > 0; j >>= 1) {
            for (int i = tid; i < np2; i += T) {
                int ixj = i ^ j;
                if (ixj > i) {
                    u64 x = a[i], y = a[ixj];
                    bool up = ((i & k) == 0);
                    if (up ? (x < y) : (x > y)) { a[i] = y; a[ixj] = x; }
                }
            }
            __syncthreads();
        }
    }
}

// ---------------- K4: top-200 via LDS bitonic sort ----------------
__global__ __launch_bounds__(1024) void k_topk(const u64* __restrict__ keys_g,
                                               const int* __restrict__ ccnt,
                                               float* __restrict__ cxArr,
                                               float* __restrict__ cyArr,
                                               float* __restrict__ out_centers,
                                               float* __restrict__ out_topvals) {
    __shared__ u64 sk[CHUNK];
    __shared__ u64 cur[512];
    const int T = 1024;
    int b = blockIdx.x;
    int tid = threadIdx.x;
    int n = ccnt[b];
    if (n > CAPC) n = CAPC;
    const u64* Kg = keys_g + (size_t)b * CAPC;
    int nch = (n + CHUNK - 1) / CHUNK;
    if (nch < 1) nch = 1;
    if (tid < 512) cur[tid] = 0;
    __syncthreads();
    for (int ch = 0; ch < nch; ch++) {
        int off = ch * CHUNK;
        int len = n - off; if (len < 0) len = 0; if (len > CHUNK) len = CHUNK;
        int np2 = 256; while (np2 < len) np2 <<= 1;
        for (int c = tid; c < np2; c += T) sk[c] = (c < len) ? Kg[off + c] : 0;
        __syncthreads();
        bitonic_desc(sk, np2, tid, T);
        if (ch == 0) {
            if (tid < TK) cur[tid] = sk[tid];
            __syncthreads();
        } else {
            if (tid < TK) cur[TK + tid] = sk[tid];
            else if (tid < 512) { if (tid >= 2 * TK) cur[tid] = 0; }
            __syncthreads();
            bitonic_desc(cur, 512, tid, T);
        }
    }
    if (tid < TK) {
        u64 w = cur[tid];
        bool valid = (w != 0ULL);
        unsigned ou = (unsigned)(w >> 19);
        unsigned ub = (ou & 0x80000000u) ? (ou & 0x7FFFFFFFu) : ~ou;
        float v = __uint_as_float(ub);
        int pix = valid ? (int)(HWSZ - 1 - (int)(w & 0x7FFFFULL)) : 0x7fffffff;
        int ys = pix >> 10;
        int xs = pix & (NW - 1);
        cxArr[b * TK + tid] = valid ? (float)xs : 1e9f;
        cyArr[b * TK + tid] = valid ? (float)ys : 1e9f;
        out_centers[(b * TK + tid) * 2 + 0] = (float)ys;
        out_centers[(b * TK + tid) * 2 + 1] = (float)xs;
        out_topvals[b * TK + tid] = valid ? v : -INFINITY;
    }
}

// ---------------- K5: assignment, 8 px/thread, float4 center loads ----------------
// Centers read 4-at-a-time via ds_read_b128 (100 LDS insts/thread vs 400 b32);
// 8 px/thread amortizes them 2x further. k ascending within each quad keeps
// the reference first-index argmin tie-break; __f*_rn math unchanged.
__global__ __launch_bounds__(256) void k_assign(const float* __restrict__ reg,
                                                const float* __restrict__ segmap,
                                                const float* __restrict__ cxArr,
                                                const float* __restrict__ cyArr,
                                                float* __restrict__ out_inst,
                                                int* __restrict__ segcnt) {
    __shared__ float scx[TK];
    __shared__ float scy[TK];
    __shared__ int lcnt[TK * NC];
    int tid = threadIdx.x;
    int base = blockIdx.x * ACH8;          // 2048 px per block, uniform b
    int b = base >> 19;
    if (tid < TK) {
        scx[tid] = cxArr[b * TK + tid];
        scy[tid] = cyArr[b * TK + tid];
    }
    for (int t = tid; t < TK * NC; t += 256) lcnt[t] = 0;
    __syncthreads();
    const float* r0 = reg + (size_t)b * 2 * HWSZ;
    const float* r1 = r0 + HWSZ;
    int pix0 = (base & (HWSZ - 1)) + tid * 8;     // 8 consecutive px, same row (8|1024)
    int y = pix0 >> 10;
    int x0 = pix0 & (NW - 1);
    float4 rxa = *(const float4*)(r0 + pix0);
    float4 rxb = *(const float4*)(r0 + pix0 + 4);
    float4 rya = *(const float4*)(r1 + pix0);
    float4 ryb = *(const float4*)(r1 + pix0 + 4);
    float fy = (float)(y + 1);
    float px[8], py[8], bd[8];
    int bk[8];
    px[0]=__fsub_rn((float)(x0+1),rxa.x); py[0]=__fsub_rn(fy,rya.x);
    px[1]=__fsub_rn((float)(x0+2),rxa.y); py[1]=__fsub_rn(fy,rya.y);
    px[2]=__fsub_rn((float)(x0+3),rxa.z); py[2]=__fsub_rn(fy,rya.z);
    px[3]=__fsub_rn((float)(x0+4),rxa.w); py[3]=__fsub_rn(fy,rya.w);
    px[4]=__fsub_rn((float)(x0+5),rxb.x); py[4]=__fsub_rn(fy,ryb.x);
    px[5]=__fsub_rn((float)(x0+6),rxb.y); py[5]=__fsub_rn(fy,ryb.y);
    px[6]=__fsub_rn((float)(x0+7),rxb.z); py[6]=__fsub_rn(fy,ryb.z);
    px[7]=__fsub_rn((float)(x0+8),rxb.w); py[7]=__fsub_rn(fy,ryb.w);
#pragma unroll
    for (int it = 0; it < 8; it++) { bd[it] = INFINITY; bk[it] = 0; }
#pragma unroll 1
    for (int k = 0; k < TK; k += 4) {
        float4 cx4 = *(const float4*)(scx + k);   // ds_read_b128, broadcast
        float4 cy4 = *(const float4*)(scy + k);
        float cxs[4] = {cx4.x, cx4.y, cx4.z, cx4.w};
        float cys[4] = {cy4.x, cy4.y, cy4.z, cy4.w};
#pragma unroll
        for (int u = 0; u < 4; u++) {             // k ascending: first-index ties
            float cx = cxs[u];
            float cy = cys[u];
#pragma unroll
            for (int it = 0; it < 8; it++) {
                float dx = __fsub_rn(px[it], cx);
                float dy = __fsub_rn(py[it], cy);
                float d2 = __fadd_rn(__fmul_rn(dx, dx), __fmul_rn(dy, dy));
                if (d2 < bd[it]) { bd[it] = d2; bk[it] = k + u; }
            }
        }
    }
    float4 sma = *(const float4*)(segmap + base + tid * 8);
    float4 smb = *(const float4*)(segmap + base + tid * 8 + 4);
    float scls[8] = {sma.x, sma.y, sma.z, sma.w, smb.x, smb.y, smb.z, smb.w};
    float oi[8];
#pragma unroll
    for (int it = 0; it < 8; it++) {
        int cls = (int)scls[it];
        int thing = (cls >= 24) ? 1 : 0;
        int inst = (bk[it] + 1) * thing;
        oi[it] = (float)inst;
        if (inst) atomicAdd(&lcnt[bk[it] * NC + cls], 1);
    }
    *(float4*)(out_inst + base + tid * 8)     = make_float4(oi[0], oi[1], oi[2], oi[3]);
    *(float4*)(out_inst + base + tid * 8 + 4) = make_float4(oi[4], oi[5], oi[6], oi[7]);
    __syncthreads();
    for (int t = tid; t < TK * NC; t += 256) {
        int v = lcnt[t];
        if (v) atomicAdd(&segcnt[b * TK * NC + t], v);
    }
}

// ---------------- K6: per-instance class argmax + size; zero o_iprob ----------------
__global__ __launch_bounds__(256) void k_stats(const int* __restrict__ segcnt,
                                               float* __restrict__ out_icls,
                                               float* __restrict__ out_isize,
                                               float* __restrict__ out_iprob,
                                               int* __restrict__ icls,
                                               int* __restrict__ isize) {
    int t = blockIdx.x * 256 + threadIdx.x;
    if (t >= NB * TK) return;
    const int* row = segcnt + (size_t)t * NC;
    int total = 0; int bc = 0; int bv = -1;
#pragma unroll
    for (int c = 0; c < NC; c++) {
        int v = row[c];
        total += v;
        if (v > bv) { bv = v; bc = c; }
    }
    out_icls[t] = (float)bc;
    out_isize[t] = (float)total;
    out_iprob[t] = 0.f;
    icls[t] = bc;
    isize[t] = total;
}

// ---------------- K7: prob sum of selected class -> o_iprob ----------------
__global__ __launch_bounds__(256) void k_probsum(const float* __restrict__ logits,
                                                 const float* __restrict__ inst_f,
                                                 const float* __restrict__ mArr,
                                                 const float* __restrict__ dArr,
                                                 const int* __restrict__ icls,
                                                 const int* __restrict__ isize,
                                                 float* __restrict__ out_iprob) {
    __shared__ float lps[TK];
    int tid = threadIdx.x;
    int base = blockIdx.x * ACH;
    int b = base >> 19;
    for (int t = tid; t < TK; t += 256) lps[t] = 0.f;
    __syncthreads();
    int p0 = base + tid * 4;
    float4 fi = *(const float4*)(inst_f + p0);
    float4 fm = *(const float4*)(mArr + p0);
    float4 fd = *(const float4*)(dArr + p0);
    float insts[4] = {fi.x, fi.y, fi.z, fi.w};
    float ms[4] = {fm.x, fm.y, fm.z, fm.w};
    float ds[4] = {fd.x, fd.y, fd.z, fd.w};
#pragma unroll
    for (int it = 0; it < 4; it++) {
        int inst = (int)insts[it];
        if (inst) {
            int p = p0 + it;
            int pix = p & (HWSZ - 1);
            int c = icls[b * TK + inst - 1];
            float xv = logits[(size_t)(b * NC + c) * HWSZ + pix];
            float pr = __fdiv_rn(expf(__fsub_rn(xv, ms[it])), ds[it]);
            atomicAdd(&lps[inst - 1], pr);
        }
    }
    __syncthreads();
    for (int t = tid; t < TK; t += 256) {
        float s = lps[t];
        if (s != 0.f) {
            float sz = fmaxf((float)isize[b * TK + t], 1.0f);
            atomicAdd(&out_iprob[b * TK + t], s / sz);
        }
    }
}

// Host: replicate _circle_constants threshold exactly (NumPy pairwise sum, f32)
static float compute_thr_keep() {
    float cdm[121];
    int t = 0;
    for (int i = 0; i < 11; i++) {
        for (int j = 0; j < 11; j++) {
            float ox = (float)(j - 5), oy = (float)(i - 5);
            float cd = sqrtf(ox * ox + oy * oy);
            float cm = (cd <= 5.0f) ? 1.0f : 0.0f;
            cdm[t++] = cd * cm;
        }
    }
    float r[8];
    for (int k = 0; k < 8; k++) r[k] = cdm[k];
    int i = 8;
    for (; i < 121 - (121 % 8); i += 8)
        for (int k = 0; k < 8; k++) r[k] += cdm[i + k];
    float res = ((r[0] + r[1]) + (r[2] + r[3])) + ((r[4] + r[5]) + (r[6] + r[7]));
    for (; i < 121; i++) res += cdm[i];
    float thr = res / 81.0f;
    double kt = -(double)thr - 1.0;
    return (float)kt;
}

extern "C" void kernel_launch(void* const* d_in, const int* in_sizes, int n_in,
                              void* d_out, int out_size, void* d_ws, size_t ws_size,
                              hipStream_t stream) {
    const float* logits = (const float*)d_in[0];
    const float* reg    = (const float*)d_in[2];
    float* out = (float*)d_out;

    // output layout (all f32)
    float* o_inst    = out;                       // B*HW
    float* o_seg     = out + 1048576;             // B*HW
    float* o_centers = out + 2097152;             // B*TK*2
    float* o_topvals = out + 2097952;             // B*TK
    float* o_icls    = out + 2098352;             // B*TK
    float* o_iprob   = out + 2098752;             // B*TK
    float* o_isize   = out + 2099152;             // B*TK
    float* o_cmap    = out + 2099552;             // B*HW

    // workspace
    u64* keys = (u64*)d_ws;                                   // NB*CAPC
    float* wsf = (float*)(keys + (size_t)NB * CAPC);
    size_t o = 0;
    int*   zreg    = (int*)(wsf + o); o += ZWORDS;            // [ccnt(8) | segcnt]
    int*   ccnt    = zreg;
    int*   segcnt  = zreg + 8;
    float* reg_pad = wsf + o; o += (size_t)NB * 2 * RPSZ;
    float* vote_pad= wsf + o; o += (size_t)NB * VPSZ;
    float* mArr    = wsf + o; o += (size_t)NB * HWSZ;
    float* dArr    = wsf + o; o += (size_t)NB * HWSZ;
    float* cxArr   = wsf + o; o += NB * TK;
    float* cyArr   = wsf + o; o += NB * TK;
    int*   icls    = (int*)(wsf + o); o += NB * TK;
    int*   isize   = (int*)(wsf + o); o += NB * TK;

    float thr_keep = compute_thr_keep();

    int gridPix  = (NB * HWSZ) / 256;    // 4096
    int gridRow  = NB * NH;              // 1024
    int gridAsg  = (NB * HWSZ) / ACH8;   // 512
    int gridAgg  = (NB * HWSZ) / ACH;    // 1024

    k_seg<<<gridPix, 256, 0, stream>>>(logits, reg, o_seg, mArr, dArr, reg_pad, vote_pad, zreg);
    k_vote<<<gridRow, 256, 0, stream>>>(reg_pad, vote_pad);
    k_pool<<<gridRow, 256, 0, stream>>>(vote_pad, o_cmap, keys, ccnt, thr_keep);
    k_topk<<<NB, 1024, 0, stream>>>(keys, ccnt, cxArr, cyArr, o_centers, o_topvals);
    k_assign<<<gridAsg, 256, 0, stream>>>(reg, o_seg, cxArr, cyArr, o_inst, segcnt);
    k_stats<<<(NB * TK + 255) / 256, 256, 0, stream>>>(segcnt, o_icls, o_isize, o_iprob, icls, isize);
    k_probsum<<<gridAgg, 256, 0, stream>>>(logits, o_inst, mArr, dArr, icls, isize, o_iprob);
}